// Round 4
// baseline (888.543 us; speedup 1.0000x reference)
//
#include <hip/hip_runtime.h>
#include <math.h>

#define N_NODES 1024
#define BATCH   64
#define F_IN    128     // D_IN + UNITS
#define UNITS   64
#define NUM_M   5
#define CAP     192     // ELL row capacity (mean nnz ~31, max ~55 for this seed)
#define FT      4       // diffusion f-tile (float4 = one LDS row)
#define NFT     32      // F_IN / FT

// ---------------- ELL build: compact dense L rows, deterministic n-order ----
__global__ void ell_build(const float* __restrict__ L, int* __restrict__ cnt,
                          int* __restrict__ cols, float* __restrict__ vals) {
    int row  = blockIdx.x * (blockDim.x >> 6) + (threadIdx.x >> 6);
    int lane = threadIdx.x & 63;
    if (row >= N_NODES) return;
    const float* Lr = L + (size_t)row * N_NODES;
    int base = 0;
    for (int seg = 0; seg < N_NODES; seg += 64) {
        float v = Lr[seg + lane];
        bool nz = (v != 0.0f);
        unsigned long long bal = __ballot(nz);
        int off = __popcll(bal & ((1ull << lane) - 1ull));
        if (nz) {
            int idx = base + off;
            if (idx < CAP) { cols[row * CAP + idx] = seg + lane; vals[row * CAP + idx] = v; }
        }
        base += __popcll(bal);
    }
    if (base > CAP) base = CAP;
    int padded = (base + 7) & ~7;
    if (padded > CAP) padded = CAP;
    for (int idx = base + lane; idx < padded; idx += 64) {
        cols[row * CAP + idx] = 0; vals[row * CAP + idx] = 0.0f;
    }
    if (lane == 0) cnt[row] = padded;
}

// ---------------- W' prep: fold Chebyshev recurrence into weights -----------
// W layout: [fan_in=640][nout], fan_in index = k*5 + m.
// W'[m][k][j]: m0 = W0-W3-W4, m1 = W1, m2 = W2, m3 = 2*W3, m4 = 2*W4
__global__ void wprep(const float* __restrict__ W, float* __restrict__ Wp, int nout) {
    int idx = blockIdx.x * blockDim.x + threadIdx.x;
    int total = NUM_M * F_IN * nout;
    if (idx >= total) return;
    int j = idx % nout;
    int k = (idx / nout) % F_IN;
    int m = idx / (nout * F_IN);
    const float* Wk = W + (size_t)(k * NUM_M) * nout;
    float v;
    if (m == 0)      v = Wk[0 * nout + j] - Wk[3 * nout + j] - Wk[4 * nout + j];
    else if (m == 3) v = 2.0f * Wk[3 * nout + j];
    else if (m == 4) v = 2.0f * Wk[4 * nout + j];
    else             v = Wk[(size_t)m * nout + j];
    Wp[idx] = v;
}

// ---------------- diffuse4: A,B,C,D f-tiles from one staged xin tile --------
// grid = (NFT, bc), block = 256, LDS = 32 KB -> 4 blocks/CU, 16 waves/CU.
// One lane per output row; one ds_read_b128 per nonzero (full FT=4 row).
// Outputs in tiled layout: buf[((b*NFT + ft)*1024 + m)*4 + f]
template <int RMUL>
__global__ __launch_bounds__(256, 4) void diffuse4(
        const int* __restrict__ cnt0, const int* __restrict__ cols0, const float* __restrict__ vals0,
        const int* __restrict__ cnt1, const int* __restrict__ cols1, const float* __restrict__ vals1,
        const float* __restrict__ inp, const float* __restrict__ hx, const float* __restrict__ r1,
        float* __restrict__ A, float* __restrict__ Bm,
        float* __restrict__ C, float* __restrict__ D, int row0) {
    __shared__ float ldsX[N_NODES * FT];   // 16 KB
    __shared__ float ldsT[N_NODES * FT];   // 16 KB
    const int b = blockIdx.y, f0 = blockIdx.x * FT;
    const int tid = threadIdx.x;

    // stage xin tile: one float4 (full tile row) per node
    for (int n = tid; n < N_NODES; n += 256) {
        size_t g = (size_t)(row0 + b * N_NODES + n);
        float4 d;
        if (f0 < UNITS) {
            d = *(const float4*)(inp + g * 64 + f0);
        } else {
            d = *(const float4*)(hx + g * 64 + (f0 - 64));
            if (RMUL) {
                float4 r = *(const float4*)(r1 + (size_t)(b * N_NODES + n) * F_IN + (f0 - 64));
                d.x *= r.x; d.y *= r.y; d.z *= r.z; d.w *= r.w;
            }
        }
        *(float4*)(ldsX + n * FT) = d;
    }
    __syncthreads();

    const size_t tbase = ((size_t)b * NFT + blockIdx.x) * N_NODES;
    float4 accR[4];

    auto gather = [&](const int* __restrict__ cnt, const int* __restrict__ cols,
                      const float* __restrict__ vals, const float* __restrict__ src) {
        #pragma unroll
        for (int k = 0; k < 4; ++k) {
            int m = tid + k * 256;
            int nn = cnt[m];
            const int*   cm = cols + m * CAP;
            const float* vm = vals + m * CAP;
            float4 acc = make_float4(0.f, 0.f, 0.f, 0.f);
            for (int j = 0; j < nn; j += 8) {     // nn is a multiple of 8
                int4   c0 = *(const int4*)(cm + j);
                int4   c1 = *(const int4*)(cm + j + 4);
                float4 w0 = *(const float4*)(vm + j);
                float4 w1 = *(const float4*)(vm + j + 4);
                int   cc[8] = {c0.x, c0.y, c0.z, c0.w, c1.x, c1.y, c1.z, c1.w};
                float ww[8] = {w0.x, w0.y, w0.z, w0.w, w1.x, w1.y, w1.z, w1.w};
                #pragma unroll
                for (int u = 0; u < 8; ++u) {
                    float4 x = *(const float4*)(src + cc[u] * FT);
                    acc.x += ww[u] * x.x; acc.y += ww[u] * x.y;
                    acc.z += ww[u] * x.z; acc.w += ww[u] * x.w;
                }
            }
            accR[k] = acc;
        }
    };

    // A = L0 @ X  -> ldsT + global
    gather(cnt0, cols0, vals0, ldsX);
    #pragma unroll
    for (int k = 0; k < 4; ++k) {
        int m = tid + k * 256;
        *(float4*)(ldsT + m * FT) = accR[k];
        *(float4*)(A + (tbase + m) * FT) = accR[k];
    }
    __syncthreads();
    // C = L0 @ A (from ldsT) -> global
    gather(cnt0, cols0, vals0, ldsT);
    #pragma unroll
    for (int k = 0; k < 4; ++k)
        *(float4*)(C + (tbase + (tid + k * 256)) * FT) = accR[k];
    // B = L1 @ X (from ldsX; keep in regs until all C-reads of ldsT are done)
    gather(cnt1, cols1, vals1, ldsX);
    __syncthreads();
    #pragma unroll
    for (int k = 0; k < 4; ++k) {
        int m = tid + k * 256;
        *(float4*)(ldsT + m * FT) = accR[k];
        *(float4*)(Bm + (tbase + m) * FT) = accR[k];
    }
    __syncthreads();
    // D = L1 @ B (from ldsT) -> global
    gather(cnt1, cols1, vals1, ldsT);
    #pragma unroll
    for (int k = 0; k < 4; ++k)
        *(float4*)(D + (tbase + (tid + k * 256)) * FT) = accR[k];
}

// ---------------- Projection: out = act(bias + sum_m Xm @ W'[m]) -----------
// 128-row x NOUT tile per block, 256 threads; thread j-range split into
// JJ=NOUT/64 chunks at tx*4 (+64) -> 2-way (free) LDS reads.
template <int NOUT, int ACT, int RMUL>
__global__ __launch_bounds__(256, 4) void proj(
        const float* __restrict__ inp, const float* __restrict__ hx, const float* __restrict__ r1,
        const float* __restrict__ X1, const float* __restrict__ X2,
        const float* __restrict__ X3, const float* __restrict__ X4,
        const float* __restrict__ Wp, const float* __restrict__ bias,
        float* __restrict__ out, int row0) {
    __shared__ float xt[32][132];            // [k][i] transposed, padded
    __shared__ float wt[32][NOUT + 4];       // [k][j], padded
    constexpr int JJ = NOUT / 64;
    const int i0   = blockIdx.x * 128;       // chunk-local row base
    const int b    = i0 >> 10;               // 1024 % 128 == 0 -> same b per block
    const int nloc = i0 & 1023;
    const int tx = threadIdx.x & 15, ty = threadIdx.x >> 4;
    float acc[8][JJ][4];
    #pragma unroll
    for (int r = 0; r < 8; ++r)
        #pragma unroll
        for (int jj = 0; jj < JJ; ++jj)
            #pragma unroll
            for (int c = 0; c < 4; ++c) acc[r][jj][c] = 0.f;

    const float* Xs[4] = {X1, X2, X3, X4};
    #pragma unroll
    for (int m = 0; m < NUM_M; ++m) {
        for (int k0 = 0; k0 < F_IN; k0 += 32) {
            __syncthreads();
            // stage X tile transposed: wave sweeps i for fixed k-quad
            for (int v = threadIdx.x; v < 1024; v += 256) {
                int q = v >> 7, i = v & 127;
                int k = k0 + q * 4;
                float4 d;
                if (m == 0) {
                    size_t g = (size_t)(row0 + i0 + i);
                    if (k < 64) d = *(const float4*)(inp + g * 64 + k);
                    else {
                        d = *(const float4*)(hx + g * 64 + (k - 64));
                        if (RMUL) {
                            float4 r = *(const float4*)(r1 + (size_t)(i0 + i) * F_IN + (k - 64));
                            d.x *= r.x; d.y *= r.y; d.z *= r.z; d.w *= r.w;
                        }
                    }
                } else {
                    const float* Xm = Xs[m - 1];
                    int ft = k >> 2;         // FT=4: float4 = full tile row
                    d = *(const float4*)(Xm + (((size_t)b * NFT + ft) * N_NODES + nloc + i) * FT);
                }
                xt[q * 4 + 0][i] = d.x; xt[q * 4 + 1][i] = d.y;
                xt[q * 4 + 2][i] = d.z; xt[q * 4 + 3][i] = d.w;
            }
            // stage W tile
            const float* Wm = Wp + (size_t)m * F_IN * NOUT + (size_t)k0 * NOUT;
            for (int v = threadIdx.x; v < 32 * (NOUT / 4); v += 256) {
                int kk = v / (NOUT / 4), q = v % (NOUT / 4);
                float4 d = *(const float4*)(Wm + (size_t)kk * NOUT + q * 4);
                *(float4*)(&wt[kk][q * 4]) = d;
            }
            __syncthreads();
            for (int kk = 0; kk < 32; ++kk) {
                float xv[8];
                *(float4*)&xv[0] = *(const float4*)&xt[kk][ty * 8];
                *(float4*)&xv[4] = *(const float4*)&xt[kk][ty * 8 + 4];
                float wv[JJ][4];
                #pragma unroll
                for (int jj = 0; jj < JJ; ++jj)
                    *(float4*)&wv[jj][0] = *(const float4*)&wt[kk][jj * 64 + tx * 4];
                #pragma unroll
                for (int r = 0; r < 8; ++r)
                    #pragma unroll
                    for (int jj = 0; jj < JJ; ++jj)
                        #pragma unroll
                        for (int c = 0; c < 4; ++c)
                            acc[r][jj][c] += xv[r] * wv[jj][c];
            }
        }
    }
    float bv[JJ][4];
    #pragma unroll
    for (int jj = 0; jj < JJ; ++jj)
        *(float4*)&bv[jj][0] = *(const float4*)(bias + jj * 64 + tx * 4);
    #pragma unroll
    for (int r = 0; r < 8; ++r) {
        size_t row = (size_t)(i0 + ty * 8 + r);
        #pragma unroll
        for (int jj = 0; jj < JJ; ++jj) {
            float a0 = acc[r][jj][0] + bv[jj][0];
            float a1 = acc[r][jj][1] + bv[jj][1];
            float a2 = acc[r][jj][2] + bv[jj][2];
            float a3 = acc[r][jj][3] + bv[jj][3];
            float4 v;
            if (ACT) { v.x = tanhf(a0); v.y = tanhf(a1); v.z = tanhf(a2); v.w = tanhf(a3); }
            else {
                v.x = 1.f / (1.f + expf(-a0)); v.y = 1.f / (1.f + expf(-a1));
                v.z = 1.f / (1.f + expf(-a2)); v.w = 1.f / (1.f + expf(-a3));
            }
            *(float4*)(out + row * NOUT + jj * 64 + tx * 4) = v;
        }
    }
}

// ---------------- Final gating: out = u*hx + (1-u)*c -----------------------
__global__ void finalize(const float* __restrict__ OUT1, const float* __restrict__ OUT2,
                         const float* __restrict__ hx, float* __restrict__ out,
                         int row0, int nrows) {
    int t = blockIdx.x * blockDim.x + threadIdx.x;
    int total = nrows * 16;                  // 16 float4 per row of 64
    if (t >= total) return;
    int i = t >> 4, q = t & 15;
    size_t g = (size_t)(row0 + i);
    float4 u = *(const float4*)(OUT1 + (size_t)i * F_IN + 64 + q * 4);
    float4 c = *(const float4*)(OUT2 + (size_t)i * UNITS + q * 4);
    float4 h = *(const float4*)(hx + g * 64 + q * 4);
    float4 o;
    o.x = u.x * h.x + (1.f - u.x) * c.x;
    o.y = u.y * h.y + (1.f - u.y) * c.y;
    o.z = u.z * h.z + (1.f - u.z) * c.z;
    o.w = u.w * h.w + (1.f - u.w) * c.w;
    *(float4*)(out + g * 64 + q * 4) = o;
}

// ---------------------------------------------------------------------------
extern "C" void kernel_launch(void* const* d_in, const int* in_sizes, int n_in,
                              void* d_out, int out_size, void* d_ws, size_t ws_size,
                              hipStream_t stream) {
    const float* inp = (const float*)d_in[0];
    const float* hx  = (const float*)d_in[1];
    const float* L0  = (const float*)d_in[2];
    const float* L1  = (const float*)d_in[3];
    const float* W1  = (const float*)d_in[4];
    const float* b1  = (const float*)d_in[5];
    const float* W2  = (const float*)d_in[6];
    const float* b2  = (const float*)d_in[7];
    float* out = (float*)d_out;

    char* ws = (char*)d_ws;
    size_t off = 0;
    auto carve = [&](size_t bytes) -> char* {
        off = (off + 255) & ~(size_t)255;
        char* p = ws + off;
        off += bytes;
        return p;
    };
    // fixed region
    int*   cnt0  = (int*)  carve(N_NODES * sizeof(int));
    int*   cols0 = (int*)  carve((size_t)N_NODES * CAP * sizeof(int));
    float* vals0 = (float*)carve((size_t)N_NODES * CAP * sizeof(float));
    int*   cnt1  = (int*)  carve(N_NODES * sizeof(int));
    int*   cols1 = (int*)  carve((size_t)N_NODES * CAP * sizeof(int));
    float* vals1 = (float*)carve((size_t)N_NODES * CAP * sizeof(float));
    float* Wp1   = (float*)carve((size_t)NUM_M * F_IN * 128 * sizeof(float));
    float* Wp2   = (float*)carve((size_t)NUM_M * F_IN * 64 * sizeof(float));

    // dynamic chunking over batch: A,B,C,D tiled + OUT1 + OUT2
    size_t xb = (size_t)N_NODES * F_IN * sizeof(float);    // 512 KB
    size_t per_batch = xb * 5 + (size_t)N_NODES * UNITS * sizeof(float);
    size_t fixed_end = (off + 255) & ~(size_t)255;
    size_t avail = (ws_size > fixed_end + 4096) ? (ws_size - fixed_end - 4096) : per_batch;
    int Bc = (int)(avail / per_batch);
    if (Bc < 1) Bc = 1;
    if (Bc > BATCH) Bc = BATCH;

    float* A    = (float*)carve((size_t)Bc * xb);
    float* Bm   = (float*)carve((size_t)Bc * xb);
    float* C    = (float*)carve((size_t)Bc * xb);
    float* D    = (float*)carve((size_t)Bc * xb);
    float* OUT1 = (float*)carve((size_t)Bc * xb);                              // [bc*1024][128]
    float* OUT2 = (float*)carve((size_t)Bc * N_NODES * UNITS * sizeof(float)); // [bc*1024][64]

    ell_build<<<N_NODES / 4, 256, 0, stream>>>(L0, cnt0, cols0, vals0);
    ell_build<<<N_NODES / 4, 256, 0, stream>>>(L1, cnt1, cols1, vals1);
    wprep<<<(NUM_M * F_IN * 128 + 255) / 256, 256, 0, stream>>>(W1, Wp1, 128);
    wprep<<<(NUM_M * F_IN * 64 + 255) / 256, 256, 0, stream>>>(W2, Wp2, 64);

    for (int b0 = 0; b0 < BATCH; b0 += Bc) {
        int bc = (BATCH - b0 < Bc) ? (BATCH - b0) : Bc;
        int nrows = bc * N_NODES;
        int row0 = b0 * N_NODES;
        dim3 dg(NFT, bc);

        diffuse4<0><<<dg, 256, 0, stream>>>(cnt0, cols0, vals0, cnt1, cols1, vals1,
                                            inp, hx, nullptr, A, Bm, C, D, row0);
        proj<128, 0, 0><<<nrows / 128, 256, 0, stream>>>(inp, hx, nullptr,
                                                         A, Bm, C, D, Wp1, b1, OUT1, row0);
        diffuse4<1><<<dg, 256, 0, stream>>>(cnt0, cols0, vals0, cnt1, cols1, vals1,
                                            inp, hx, OUT1, A, Bm, C, D, row0);
        proj<64, 1, 1><<<nrows / 128, 256, 0, stream>>>(inp, hx, OUT1,
                                                        A, Bm, C, D, Wp2, b2, OUT2, row0);
        finalize<<<(nrows * 16 + 255) / 256, 256, 0, stream>>>(OUT1, OUT2, hx, out, row0, nrows);
    }
}

// Round 5
// 701.571 us; speedup vs baseline: 1.2665x; 1.2665x over previous
//
#include <hip/hip_runtime.h>
#include <math.h>

#define N_NODES 1024
#define BATCH   64
#define F_IN    128     // D_IN + UNITS
#define UNITS   64
#define NUM_M   5
#define CAP     192     // ELL row capacity (max row degree ~55 for this seed)
#define FT      8       // diffusion f-tile
#define NFT     16      // F_IN / FT

// ---------------- ELL build: column-major packed (col,val) pairs ------------
// ell[j*1024 + row] = float2(col_as_float_bits, val); cnt[row] = nnz padded to x4.
// Column-major => at step j a wave's consecutive rows read contiguous memory.
__global__ void ell_build(const float* __restrict__ L, int* __restrict__ cnt,
                          float2* __restrict__ ell) {
    int row  = blockIdx.x * (blockDim.x >> 6) + (threadIdx.x >> 6);
    int lane = threadIdx.x & 63;
    if (row >= N_NODES) return;
    const float* Lr = L + (size_t)row * N_NODES;
    int base = 0;
    for (int seg = 0; seg < N_NODES; seg += 64) {
        float v = Lr[seg + lane];
        bool nz = (v != 0.0f);
        unsigned long long bal = __ballot(nz);
        int off = __popcll(bal & ((1ull << lane) - 1ull));
        if (nz) {
            int idx = base + off;
            if (idx < CAP) ell[(size_t)idx * N_NODES + row] =
                               make_float2(__int_as_float(seg + lane), v);
        }
        base += __popcll(bal);
    }
    if (base > CAP) base = CAP;
    int padded = (base + 3) & ~3;
    if (padded > CAP) padded = CAP;
    for (int idx = base + lane; idx < padded; idx += 64)
        ell[(size_t)idx * N_NODES + row] = make_float2(__int_as_float(0), 0.0f);
    if (lane == 0) cnt[row] = padded;
}

// ---------------- W' prep: fold Chebyshev recurrence into weights -----------
// W layout: [fan_in=640][nout], fan_in index = k*5 + m.
// W'[m][k][j]: m0 = W0-W3-W4, m1 = W1, m2 = W2, m3 = 2*W3, m4 = 2*W4
__global__ void wprep(const float* __restrict__ W, float* __restrict__ Wp, int nout) {
    int idx = blockIdx.x * blockDim.x + threadIdx.x;
    int total = NUM_M * F_IN * nout;
    if (idx >= total) return;
    int j = idx % nout;
    int k = (idx / nout) % F_IN;
    int m = idx / (nout * F_IN);
    const float* Wk = W + (size_t)(k * NUM_M) * nout;
    float v;
    if (m == 0)      v = Wk[0 * nout + j] - Wk[3 * nout + j] - Wk[4 * nout + j];
    else if (m == 3) v = 2.0f * Wk[3 * nout + j];
    else if (m == 4) v = 2.0f * Wk[4 * nout + j];
    else             v = Wk[(size_t)m * nout + j];
    Wp[idx] = v;
}

// ---------------- shared gather core (FT=8, 2 lanes per row) ---------------
// Returns 8 float4 partials for rows mg + k*128, features f0 + fg*4.
__device__ __forceinline__ void gather8(
        const int* __restrict__ cnt, const float2* __restrict__ ell,
        const float* __restrict__ ldsX, int mg, int fg, float4* accR) {
    #pragma unroll
    for (int k = 0; k < 8; ++k) {
        int m = mg + k * 128;
        int nn = cnt[m];
        float4 acc = make_float4(0.f, 0.f, 0.f, 0.f);
        for (int j = 0; j < nn; j += 4) {        // nn is a multiple of 4
            float2 p0 = ell[(size_t)(j + 0) * N_NODES + m];
            float2 p1 = ell[(size_t)(j + 1) * N_NODES + m];
            float2 p2 = ell[(size_t)(j + 2) * N_NODES + m];
            float2 p3 = ell[(size_t)(j + 3) * N_NODES + m];
            float4 x0 = *(const float4*)(ldsX + __float_as_int(p0.x) * FT + fg * 4);
            float4 x1 = *(const float4*)(ldsX + __float_as_int(p1.x) * FT + fg * 4);
            float4 x2 = *(const float4*)(ldsX + __float_as_int(p2.x) * FT + fg * 4);
            float4 x3 = *(const float4*)(ldsX + __float_as_int(p3.x) * FT + fg * 4);
            acc.x += p0.y * x0.x; acc.y += p0.y * x0.y; acc.z += p0.y * x0.z; acc.w += p0.y * x0.w;
            acc.x += p1.y * x1.x; acc.y += p1.y * x1.y; acc.z += p1.y * x1.z; acc.w += p1.y * x1.w;
            acc.x += p2.y * x2.x; acc.y += p2.y * x2.y; acc.z += p2.y * x2.z; acc.w += p2.y * x2.w;
            acc.x += p3.y * x3.x; acc.y += p3.y * x3.y; acc.z += p3.y * x3.z; acc.w += p3.y * x3.w;
        }
        accR[k] = acc;
    }
}

// ---------------- diffuseAB: A = L0@X, B = L1@X from one staged xin tile ----
// grid = (NFT, bc), block = 256, LDS = 32 KB -> 4 blocks/CU.
// Outputs tiled: buf[((b*NFT + ft)*1024 + m)*8 + f]
template <int RMUL>
__global__ __launch_bounds__(256, 4) void diffuseAB(
        const int* __restrict__ cnt0, const float2* __restrict__ ell0,
        const int* __restrict__ cnt1, const float2* __restrict__ ell1,
        const float* __restrict__ inp, const float* __restrict__ hx, const float* __restrict__ r1,
        float* __restrict__ A, float* __restrict__ Bm, int row0) {
    __shared__ float ldsX[N_NODES * FT];   // 32 KB
    const int b = blockIdx.y, f0 = blockIdx.x * FT;
    const int tid = threadIdx.x;

    for (int v = tid; v < N_NODES * 2; v += 256) {
        int n = v >> 1, q = (v & 1) * 4;
        size_t g = (size_t)(row0 + b * N_NODES + n);
        float4 d;
        if (f0 < UNITS) {
            d = *(const float4*)(inp + g * 64 + f0 + q);
        } else {
            d = *(const float4*)(hx + g * 64 + (f0 - 64) + q);
            if (RMUL) {
                float4 r = *(const float4*)(r1 + (size_t)(b * N_NODES + n) * F_IN + (f0 - 64) + q);
                d.x *= r.x; d.y *= r.y; d.z *= r.z; d.w *= r.w;
            }
        }
        *(float4*)(ldsX + n * FT + q) = d;
    }
    __syncthreads();

    const int fg = tid & 1, mg = tid >> 1;
    const size_t tbase = ((size_t)b * NFT + blockIdx.x) * N_NODES;
    float4 accR[8];

    gather8(cnt0, ell0, ldsX, mg, fg, accR);
    #pragma unroll
    for (int k = 0; k < 8; ++k)
        *(float4*)(A + (tbase + (mg + k * 128)) * FT + fg * 4) = accR[k];

    gather8(cnt1, ell1, ldsX, mg, fg, accR);
    #pragma unroll
    for (int k = 0; k < 8; ++k)
        *(float4*)(Bm + (tbase + (mg + k * 128)) * FT + fg * 4) = accR[k];
}

// ---------------- diffuseStep: dst = L @ src (both tiled layout) ------------
__global__ __launch_bounds__(256, 4) void diffuseStep(
        const int* __restrict__ cnt, const float2* __restrict__ ell,
        const float* __restrict__ src, float* __restrict__ dst) {
    __shared__ float ldsX[N_NODES * FT];   // 32 KB
    const int tid = threadIdx.x;
    const size_t tbase = ((size_t)blockIdx.y * NFT + blockIdx.x) * N_NODES;

    for (int v = tid; v < N_NODES * 2; v += 256) {
        int n = v >> 1, q = (v & 1) * 4;
        *(float4*)(ldsX + n * FT + q) = *(const float4*)(src + (tbase + n) * FT + q);
    }
    __syncthreads();

    const int fg = tid & 1, mg = tid >> 1;
    float4 accR[8];
    gather8(cnt, ell, ldsX, mg, fg, accR);
    #pragma unroll
    for (int k = 0; k < 8; ++k)
        *(float4*)(dst + (tbase + (mg + k * 128)) * FT + fg * 4) = accR[k];
}

// ---------------- Projection: out = act(bias + sum_m Xm @ W'[m]) -----------
// 128-row x NOUT tile per block, 256 threads; thread j-range split into
// JJ=NOUT/64 chunks at tx*4 (+64) -> 2-way (free) LDS reads.
template <int NOUT, int ACT, int RMUL>
__global__ __launch_bounds__(256, 4) void proj(
        const float* __restrict__ inp, const float* __restrict__ hx, const float* __restrict__ r1,
        const float* __restrict__ X1, const float* __restrict__ X2,
        const float* __restrict__ X3, const float* __restrict__ X4,
        const float* __restrict__ Wp, const float* __restrict__ bias,
        float* __restrict__ out, int row0) {
    __shared__ float xt[32][132];            // [k][i] transposed, padded
    __shared__ float wt[32][NOUT + 4];       // [k][j], padded
    constexpr int JJ = NOUT / 64;
    const int i0   = blockIdx.x * 128;       // chunk-local row base
    const int b    = i0 >> 10;               // 1024 % 128 == 0 -> same b per block
    const int nloc = i0 & 1023;
    const int tx = threadIdx.x & 15, ty = threadIdx.x >> 4;
    float acc[8][JJ][4];
    #pragma unroll
    for (int r = 0; r < 8; ++r)
        #pragma unroll
        for (int jj = 0; jj < JJ; ++jj)
            #pragma unroll
            for (int c = 0; c < 4; ++c) acc[r][jj][c] = 0.f;

    const float* Xs[4] = {X1, X2, X3, X4};
    #pragma unroll
    for (int m = 0; m < NUM_M; ++m) {
        for (int k0 = 0; k0 < F_IN; k0 += 32) {
            __syncthreads();
            // stage X tile transposed: wave sweeps i for fixed k-quad
            for (int v = threadIdx.x; v < 1024; v += 256) {
                int q = v >> 7, i = v & 127;
                int k = k0 + q * 4;
                float4 d;
                if (m == 0) {
                    size_t g = (size_t)(row0 + i0 + i);
                    if (k < 64) d = *(const float4*)(inp + g * 64 + k);
                    else {
                        d = *(const float4*)(hx + g * 64 + (k - 64));
                        if (RMUL) {
                            float4 r = *(const float4*)(r1 + (size_t)(i0 + i) * F_IN + (k - 64));
                            d.x *= r.x; d.y *= r.y; d.z *= r.z; d.w *= r.w;
                        }
                    }
                } else {
                    const float* Xm = Xs[m - 1];
                    int ft = k >> 3, kq = k & 7;     // FT=8 tiled layout
                    d = *(const float4*)(Xm + (((size_t)b * NFT + ft) * N_NODES + nloc + i) * FT + kq);
                }
                xt[q * 4 + 0][i] = d.x; xt[q * 4 + 1][i] = d.y;
                xt[q * 4 + 2][i] = d.z; xt[q * 4 + 3][i] = d.w;
            }
            // stage W tile
            const float* Wm = Wp + (size_t)m * F_IN * NOUT + (size_t)k0 * NOUT;
            for (int v = threadIdx.x; v < 32 * (NOUT / 4); v += 256) {
                int kk = v / (NOUT / 4), q = v % (NOUT / 4);
                float4 d = *(const float4*)(Wm + (size_t)kk * NOUT + q * 4);
                *(float4*)(&wt[kk][q * 4]) = d;
            }
            __syncthreads();
            for (int kk = 0; kk < 32; ++kk) {
                float xv[8];
                *(float4*)&xv[0] = *(const float4*)&xt[kk][ty * 8];
                *(float4*)&xv[4] = *(const float4*)&xt[kk][ty * 8 + 4];
                float wv[JJ][4];
                #pragma unroll
                for (int jj = 0; jj < JJ; ++jj)
                    *(float4*)&wv[jj][0] = *(const float4*)&wt[kk][jj * 64 + tx * 4];
                #pragma unroll
                for (int r = 0; r < 8; ++r)
                    #pragma unroll
                    for (int jj = 0; jj < JJ; ++jj)
                        #pragma unroll
                        for (int c = 0; c < 4; ++c)
                            acc[r][jj][c] += xv[r] * wv[jj][c];
            }
        }
    }
    float bv[JJ][4];
    #pragma unroll
    for (int jj = 0; jj < JJ; ++jj)
        *(float4*)&bv[jj][0] = *(const float4*)(bias + jj * 64 + tx * 4);
    #pragma unroll
    for (int r = 0; r < 8; ++r) {
        size_t row = (size_t)(i0 + ty * 8 + r);
        #pragma unroll
        for (int jj = 0; jj < JJ; ++jj) {
            float a0 = acc[r][jj][0] + bv[jj][0];
            float a1 = acc[r][jj][1] + bv[jj][1];
            float a2 = acc[r][jj][2] + bv[jj][2];
            float a3 = acc[r][jj][3] + bv[jj][3];
            float4 v;
            if (ACT) { v.x = tanhf(a0); v.y = tanhf(a1); v.z = tanhf(a2); v.w = tanhf(a3); }
            else {
                v.x = 1.f / (1.f + expf(-a0)); v.y = 1.f / (1.f + expf(-a1));
                v.z = 1.f / (1.f + expf(-a2)); v.w = 1.f / (1.f + expf(-a3));
            }
            *(float4*)(out + row * NOUT + jj * 64 + tx * 4) = v;
        }
    }
}

// ---------------- Final gating: out = u*hx + (1-u)*c -----------------------
__global__ void finalize(const float* __restrict__ OUT1, const float* __restrict__ OUT2,
                         const float* __restrict__ hx, float* __restrict__ out,
                         int row0, int nrows) {
    int t = blockIdx.x * blockDim.x + threadIdx.x;
    int total = nrows * 16;                  // 16 float4 per row of 64
    if (t >= total) return;
    int i = t >> 4, q = t & 15;
    size_t g = (size_t)(row0 + i);
    float4 u = *(const float4*)(OUT1 + (size_t)i * F_IN + 64 + q * 4);
    float4 c = *(const float4*)(OUT2 + (size_t)i * UNITS + q * 4);
    float4 h = *(const float4*)(hx + g * 64 + q * 4);
    float4 o;
    o.x = u.x * h.x + (1.f - u.x) * c.x;
    o.y = u.y * h.y + (1.f - u.y) * c.y;
    o.z = u.z * h.z + (1.f - u.z) * c.z;
    o.w = u.w * h.w + (1.f - u.w) * c.w;
    *(float4*)(out + g * 64 + q * 4) = o;
}

// ---------------------------------------------------------------------------
extern "C" void kernel_launch(void* const* d_in, const int* in_sizes, int n_in,
                              void* d_out, int out_size, void* d_ws, size_t ws_size,
                              hipStream_t stream) {
    const float* inp = (const float*)d_in[0];
    const float* hx  = (const float*)d_in[1];
    const float* L0  = (const float*)d_in[2];
    const float* L1  = (const float*)d_in[3];
    const float* W1  = (const float*)d_in[4];
    const float* b1  = (const float*)d_in[5];
    const float* W2  = (const float*)d_in[6];
    const float* b2  = (const float*)d_in[7];
    float* out = (float*)d_out;

    char* ws = (char*)d_ws;
    size_t off = 0;
    auto carve = [&](size_t bytes) -> char* {
        off = (off + 255) & ~(size_t)255;
        char* p = ws + off;
        off += bytes;
        return p;
    };
    // fixed region
    int*    cnt0 = (int*)   carve(N_NODES * sizeof(int));
    float2* ell0 = (float2*)carve((size_t)N_NODES * CAP * sizeof(float2));
    int*    cnt1 = (int*)   carve(N_NODES * sizeof(int));
    float2* ell1 = (float2*)carve((size_t)N_NODES * CAP * sizeof(float2));
    float*  Wp1  = (float*) carve((size_t)NUM_M * F_IN * 128 * sizeof(float));
    float*  Wp2  = (float*) carve((size_t)NUM_M * F_IN * 64 * sizeof(float));

    // dynamic chunking over batch: A,B,C,D tiled + OUT1 + OUT2
    size_t xb = (size_t)N_NODES * F_IN * sizeof(float);    // 512 KB
    size_t per_batch = xb * 5 + (size_t)N_NODES * UNITS * sizeof(float);
    size_t fixed_end = (off + 255) & ~(size_t)255;
    size_t avail = (ws_size > fixed_end + 4096) ? (ws_size - fixed_end - 4096) : per_batch;
    int Bc = (int)(avail / per_batch);
    if (Bc < 1) Bc = 1;
    if (Bc > BATCH) Bc = BATCH;

    float* A    = (float*)carve((size_t)Bc * xb);
    float* Bm   = (float*)carve((size_t)Bc * xb);
    float* C    = (float*)carve((size_t)Bc * xb);
    float* D    = (float*)carve((size_t)Bc * xb);
    float* OUT1 = (float*)carve((size_t)Bc * xb);                              // [bc*1024][128]
    float* OUT2 = (float*)carve((size_t)Bc * N_NODES * UNITS * sizeof(float)); // [bc*1024][64]

    ell_build<<<N_NODES / 4, 256, 0, stream>>>(L0, cnt0, ell0);
    ell_build<<<N_NODES / 4, 256, 0, stream>>>(L1, cnt1, ell1);
    wprep<<<(NUM_M * F_IN * 128 + 255) / 256, 256, 0, stream>>>(W1, Wp1, 128);
    wprep<<<(NUM_M * F_IN * 64 + 255) / 256, 256, 0, stream>>>(W2, Wp2, 64);

    for (int b0 = 0; b0 < BATCH; b0 += Bc) {
        int bc = (BATCH - b0 < Bc) ? (BATCH - b0) : Bc;
        int nrows = bc * N_NODES;
        int row0 = b0 * N_NODES;
        dim3 dg(NFT, bc);

        diffuseAB<0><<<dg, 256, 0, stream>>>(cnt0, ell0, cnt1, ell1,
                                             inp, hx, nullptr, A, Bm, row0);
        diffuseStep<<<dg, 256, 0, stream>>>(cnt0, ell0, A, C);
        diffuseStep<<<dg, 256, 0, stream>>>(cnt1, ell1, Bm, D);
        proj<128, 0, 0><<<nrows / 128, 256, 0, stream>>>(inp, hx, nullptr,
                                                         A, Bm, C, D, Wp1, b1, OUT1, row0);
        diffuseAB<1><<<dg, 256, 0, stream>>>(cnt0, ell0, cnt1, ell1,
                                             inp, hx, OUT1, A, Bm, row0);
        diffuseStep<<<dg, 256, 0, stream>>>(cnt0, ell0, A, C);
        diffuseStep<<<dg, 256, 0, stream>>>(cnt1, ell1, Bm, D);
        proj<64, 1, 1><<<nrows / 128, 256, 0, stream>>>(inp, hx, OUT1,
                                                        A, Bm, C, D, Wp2, b2, OUT2, row0);
        finalize<<<(nrows * 16 + 255) / 256, 256, 0, stream>>>(OUT1, OUT2, hx, out, row0, nrows);
    }
}